// Round 5
// baseline (793.229 us; speedup 1.0000x reference)
//
#include <hip/hip_runtime.h>
#include <hip/hip_bf16.h>
#include <cmath>
#include <cstdint>

using bf16 = __hip_bfloat16;
typedef __attribute__((ext_vector_type(8))) short short8;
typedef __attribute__((ext_vector_type(4))) float f32x4;
typedef __attribute__((ext_vector_type(4))) unsigned short ushort4v;

#define T_DIM 2048
#define B_DIM 8
#define D_DIM 1024
#define MROWS (T_DIM*B_DIM)   // 16384
#define N8 (B_DIM*D_DIM)      // 8192

__device__ __forceinline__ float b2f(bf16 x) { return __bfloat162float(x); }
__device__ __forceinline__ bf16  f2b(float x) { return __float2bfloat16(x); }
__device__ __forceinline__ float us2f(unsigned short u) {
    union { unsigned int i; float f; } x; x.i = ((unsigned int)u) << 16; return x.f;
}
__device__ __forceinline__ unsigned short f2us(float f) {
    bf16 b = __float2bfloat16(f);
    return *(unsigned short*)&b;
}

// async global->LDS, 16B per lane. LDS dest must be wave-uniform base + lane*16.
__device__ __forceinline__ void gload_lds16(const bf16* g, char* l) {
    __builtin_amdgcn_global_load_lds(
        (const __attribute__((address_space(1))) unsigned int*)g,
        (__attribute__((address_space(3))) unsigned int*)l,
        16, 0, 0);
}

// ---------------- LayerNorm: f32 [16384,1024] -> bf16 ----------------
__global__ __launch_bounds__(256) void ln_kernel(const float* __restrict__ x,
                                                 bf16* __restrict__ h) {
    const int row = blockIdx.x;
    const int tid = threadIdx.x;
    const float4 v = ((const float4*)(x + (size_t)row * D_DIM))[tid];
    float s1 = v.x + v.y + v.z + v.w;
    float s2 = v.x*v.x + v.y*v.y + v.z*v.z + v.w*v.w;
    #pragma unroll
    for (int off = 32; off > 0; off >>= 1) {
        s1 += __shfl_down(s1, off);
        s2 += __shfl_down(s2, off);
    }
    __shared__ float red[8];
    const int lane = tid & 63, wv = tid >> 6;
    if (lane == 0) { red[wv*2] = s1; red[wv*2+1] = s2; }
    __syncthreads();
    s1 = red[0] + red[2] + red[4] + red[6];
    s2 = red[1] + red[3] + red[5] + red[7];
    const float mean = s1 * (1.0f / D_DIM);
    const float var  = s2 * (1.0f / D_DIM) - mean * mean;
    const float rstd = rsqrtf(var + 1.1754943508222875e-38f);
    bf16* hr = h + (size_t)row * D_DIM + tid * 4;
    hr[0] = f2b((v.x - mean) * rstd);
    hr[1] = f2b((v.y - mean) * rstd);
    hr[2] = f2b((v.z - mean) * rstd);
    hr[3] = f2b((v.w - mean) * rstd);
}

// ---------------- exp(pos_bias) f32 -> bf16 ----------------
__global__ __launch_bounds__(256) void expw_kernel(const float* __restrict__ p,
                                                   bf16* __restrict__ w, int n4) {
    const int i = blockIdx.x * 256 + threadIdx.x;
    if (i < n4) {
        const float4 v = ((const float4*)p)[i];
        bf16* o = w + (size_t)i * 4;
        o[0] = f2b(expf(v.x)); o[1] = f2b(expf(v.y));
        o[2] = f2b(expf(v.z)); o[3] = f2b(expf(v.w));
    }
}

// ---------------- f32 -> bf16 convert ----------------
__global__ __launch_bounds__(256) void cvt_kernel(const float* __restrict__ p,
                                                  bf16* __restrict__ w, int n4) {
    const int i = blockIdx.x * 256 + threadIdx.x;
    if (i < n4) {
        const float4 v = ((const float4*)p)[i];
        bf16* o = w + (size_t)i * 4;
        o[0] = f2b(v.x); o[1] = f2b(v.y); o[2] = f2b(v.z); o[3] = f2b(v.w);
    }
}

// ---- fc1 weight convert + row-interleave: dst row 2d = x1 row d, 2d+1 = gate row d ----
__global__ __launch_bounds__(256) void cvt_ilv_kernel(const float* __restrict__ p,
                                                      bf16* __restrict__ w) {
    const int i = blockIdx.x * 256 + threadIdx.x;   // over 2048*1024/4
    const size_t j = (size_t)i * 4;
    const int drow = (int)(j >> 10);
    const int dcol = (int)(j & 1023);
    const int srow = (drow >> 1) + (drow & 1) * 1024;
    const float4 v = *(const float4*)(p + (size_t)srow * 1024 + dcol);
    bf16* o = w + j;
    o[0] = f2b(v.x); o[1] = f2b(v.y); o[2] = f2b(v.z); o[3] = f2b(v.w);
}

// -------- transpose [2048,8192] -> interleaved [16384,2048]: row 2u=ek^T, 2u+1=(ek*v)^T --------
__global__ __launch_bounds__(256) void transpose_ekv(
        const unsigned short* __restrict__ ek, const unsigned short* __restrict__ vv,
        unsigned short* __restrict__ EKi) {
    __shared__ unsigned short le[64][68];
    __shared__ unsigned short lv[64][68];
    const int t0 = blockIdx.y * 64;
    const int n0 = blockIdx.x * 64;
    const int tid = threadIdx.x;
    const int r = tid >> 4;
    const int c = tid & 15;
    #pragma unroll
    for (int rr = 0; rr < 4; rr++) {
        const int row = rr * 16 + r;
        const size_t gi = (size_t)(t0 + row) * N8 + n0 + c * 4;
        const ushort4v e = *(const ushort4v*)(ek + gi);
        const ushort4v v = *(const ushort4v*)(vv + gi);
        *(ushort4v*)&le[row][c * 4] = e;
        *(ushort4v*)&lv[row][c * 4] = v;
    }
    __syncthreads();
    #pragma unroll
    for (int rr = 0; rr < 4; rr++) {
        const int nrow = rr * 16 + r;
        ushort4v eo, evo;
        #pragma unroll
        for (int j = 0; j < 4; j++) {
            const int tl = c * 4 + j;
            const unsigned short e = le[tl][nrow];
            const unsigned short v = lv[tl][nrow];
            eo[j]  = e;
            evo[j] = f2us(us2f(e) * us2f(v));
        }
        const size_t go = (size_t)(2 * (n0 + nrow)) * T_DIM + t0 + c * 4;
        *(ushort4v*)(EKi + go)         = eo;   // den row (2u)
        *(ushort4v*)(EKi + go + T_DIM) = evo;  // num row (2u+1)
    }
}

// ================= 256x256 8-phase GEMM (T1+T2+T3+T4+T5) ====================
// C[m,n] = sum_k A[m,k]*Bt[n,k].  512 thr = 8 waves (2x4), BK=64, 2 K-tiles/iter.
// LDS 128KB = 2 bufs x 4 blocks (A0,A1,B0,B1) of 16KB.
// Block layout: [ksub(2) x 8KB][row(128) x 64B][kc(32) x bf16]; physical byte
// addr = linear ^ ((linear>>9)&1)<<5  -> conflict-free ds_read_b128.
// DMA dest linear; source k pre-swizzled (inverse involution); read k swizzled.
// EPI_ATTN / EPI_GLU: B rows interleaved pairs; partner value via shfl_xor(1).
enum { EPI_QKV = 0, EPI_BIAS_F32 = 1, EPI_FC2SUM = 2, EPI_STORE_BF16 = 3,
       EPI_BIAS_BF16 = 4, EPI_ATTN = 5, EPI_GLU = 6 };

#define BAR() __builtin_amdgcn_s_barrier()

#define RD_A(ABASE, MOFF)                                                       \
    _Pragma("unroll")                                                           \
    for (int m = 0; m < 4; m++) {                                               \
        a[m][0] = *(const short8*)(lds + (ABASE) + (MOFF + m) * 1024);          \
        a[m][1] = *(const short8*)(lds + (ABASE) + (MOFF + m) * 1024 + 8192);   \
    }

#define RD_B(BBASE, NOFF, BREG)                                                 \
    _Pragma("unroll")                                                           \
    for (int n = 0; n < 2; n++) {                                               \
        BREG[n][0] = *(const short8*)(lds + (BBASE) + (NOFF + n) * 1024);       \
        BREG[n][1] = *(const short8*)(lds + (BBASE) + (NOFF + n) * 1024 + 8192);\
    }

#define MFMA_QUAD(MB, NB, BREG)                                               \
    __builtin_amdgcn_s_setprio(1);                                            \
    _Pragma("unroll")                                                         \
    for (int m = 0; m < 4; m++) {                                             \
        _Pragma("unroll")                                                     \
        for (int n = 0; n < 2; n++) {                                         \
            acc[MB + m][NB + n] = __builtin_amdgcn_mfma_f32_16x16x32_bf16(    \
                a[m][0], BREG[n][0], acc[MB + m][NB + n], 0, 0, 0);           \
            acc[MB + m][NB + n] = __builtin_amdgcn_mfma_f32_16x16x32_bf16(    \
                a[m][1], BREG[n][1], acc[MB + m][NB + n], 0, 0, 0);           \
        }                                                                     \
    }                                                                         \
    __builtin_amdgcn_s_setprio(0);

template <int M, int N, int K, int EPI>
__global__ __launch_bounds__(512, 2)
void gemm8(const bf16* __restrict__ A, const bf16* __restrict__ Bt,
           const float* __restrict__ bias,
           void* __restrict__ o0, void* __restrict__ o1, void* __restrict__ o2,
           const float* __restrict__ e1, const float* __restrict__ e2) {
    constexpr int NK = K / 64;
    constexpr int NIT = NK / 2;
    constexpr int KMASK = NK - 1;
    __shared__ char lds[131072];
    const int tid = threadIdx.x;
    const int lane = tid & 63;
    const int wid = tid >> 6;
    const int wr = wid >> 2, wc = wid & 3;
    const int lr = lane & 15;

    // XCD-aware bijective swizzle (all grids are multiples of 8 blocks)
    const int nwg = gridDim.x * gridDim.y;
    int lin = blockIdx.y * gridDim.x + blockIdx.x;
    lin = (lin & 7) * (nwg >> 3) + (lin >> 3);
    const int bx = lin % gridDim.x, by = lin / gridDim.x;
    const int m0 = by * 256, n0 = bx * 256;

    // staging constants: thread tid fetches the logical element whose swizzled
    // physical slot is tid*16 (linear DMA dest).
    const int srow  = tid >> 2;                                    // 0..127
    const int skcol = ((tid & 3) * 8) ^ (((tid >> 5) & 1) << 4);   // elements
    const int sdst  = tid * 16;                                    // bytes

    // read-side swizzle: 16B slot (lane>>4), XOR bit5 with row bit3 (lane bit3)
    const int ck = ((lane >> 4) * 16) ^ (((lane >> 3) & 1) << 5);
    const int abase0 = wr * 16384 + lr * 64 + ck;
    const int abase1 = 65536 + abase0;
    const int bbase0 = 32768 + (wc >> 1) * 16384 + (wc & 1) * 4096 + lr * 64 + ck;
    const int bbase1 = 65536 + bbase0;

    auto STAGE = [&](const bf16* P, int r0, int kt, int ldsoff) {
        const bf16* src = P + (size_t)(r0 + srow) * K + kt + skcol;
        gload_lds16(src,      lds + ldsoff + sdst);
        gload_lds16(src + 32, lds + ldsoff + 8192 + sdst);
    };

    f32x4 acc[8][4] = {};
    short8 a[4][2], blo[2][2], bhi[2][2];

    // prologue: tile0 (all 4 blocks) + B0(1), A0(1); leave last 2 blocks in flight
    STAGE(A,  m0,       0, 0);
    STAGE(A,  m0 + 128, 0, 16384);
    STAGE(Bt, n0,       0, 32768);
    STAGE(Bt, n0 + 128, 0, 49152);
    STAGE(Bt, n0,      64, 65536 + 32768);
    STAGE(A,  m0,      64, 65536);
    asm volatile("s_waitcnt vmcnt(4)");
    BAR();

    for (int i = 0; i < NIT; ++i) {
        const int t1k = ((2 * i + 1) & KMASK) * 64;
        const int t2k = ((2 * i + 2) & KMASK) * 64;
        const int t3k = ((2 * i + 3) & KMASK) * 64;
        // p1: (mlo,nlo) of tile U(buf0); stage B1(V)
        RD_A(abase0, 0); RD_B(bbase0, 0, blo);
        STAGE(Bt, n0 + 128, t1k, 65536 + 49152);
        BAR(); MFMA_QUAD(0, 0, blo); BAR();
        // p2: (mlo,nhi); stage A1(V)
        RD_B(bbase0, 2, bhi);
        STAGE(A, m0 + 128, t1k, 65536 + 16384);
        BAR(); MFMA_QUAD(0, 2, bhi); BAR();
        // p3: (mhi,nhi); stage B0(t+2)
        RD_A(abase0, 4);
        STAGE(Bt, n0, t2k, 32768);
        BAR(); MFMA_QUAD(4, 2, bhi); BAR();
        // p4: (mhi,nlo); stage A0(t+2); counted wait -> tile V fully landed
        STAGE(A, m0, t2k, 0);
        asm volatile("s_waitcnt vmcnt(4)");
        BAR(); MFMA_QUAD(4, 0, blo); BAR();
        // p5: (mlo,nlo) of tile V(buf1); stage A1(t+2)
        RD_A(abase1, 0); RD_B(bbase1, 0, blo);
        STAGE(A, m0 + 128, t2k, 16384);
        BAR(); MFMA_QUAD(0, 0, blo); BAR();
        // p6: (mlo,nhi); stage B1(t+2)
        RD_B(bbase1, 2, bhi);
        STAGE(Bt, n0 + 128, t2k, 49152);
        BAR(); MFMA_QUAD(0, 2, bhi); BAR();
        // p7: (mhi,nhi); stage B0(t+3)
        RD_A(abase1, 4);
        STAGE(Bt, n0, t3k, 65536 + 32768);
        BAR(); MFMA_QUAD(4, 2, bhi); BAR();
        // p8: (mhi,nlo); stage A0(t+3); counted wait -> tile t+2 fully landed
        STAGE(A, m0, t3k, 65536);
        asm volatile("s_waitcnt vmcnt(4)");
        BAR(); MFMA_QUAD(4, 0, blo); BAR();
    }
    asm volatile("s_waitcnt vmcnt(0)");  // drain DMA before LDS teardown

    // epilogue
    const int rb = (lane >> 4) * 4;
    #pragma unroll
    for (int mm = 0; mm < 8; mm++) {
        #pragma unroll
        for (int nn = 0; nn < 4; nn++) {
            const int col = n0 + wc * 64 + nn * 16 + lr;
            float bv = 0.f;
            if constexpr (EPI == EPI_GLU) bv = bias[(col & 1) * 1024 + (col >> 1)];
            else if constexpr (EPI != EPI_STORE_BF16 && EPI != EPI_ATTN) bv = bias[col];
            const int row0 = m0 + wr * 128 + mm * 16 + rb;
            #pragma unroll
            for (int r = 0; r < 4; r++) {
                const int row = row0 + r;
                const float c = acc[mm][nn][r] + bv;
                if constexpr (EPI == EPI_QKV) {
                    const int seg = col >> 10;
                    const int nc = col & 1023;
                    const size_t idx = (size_t)row * 1024 + nc;
                    if (seg == 0)      ((bf16*)o0)[idx] = f2b(1.f / (1.f + expf(-c)));
                    else if (seg == 1) ((bf16*)o1)[idx] = f2b(expf(c));
                    else               ((bf16*)o2)[idx] = f2b(c);
                } else if constexpr (EPI == EPI_BIAS_F32) {
                    ((float*)o0)[(size_t)row * N + col] = c;
                } else if constexpr (EPI == EPI_STORE_BF16 || EPI == EPI_BIAS_BF16) {
                    ((bf16*)o0)[(size_t)row * N + col] = f2b(c);
                } else if constexpr (EPI == EPI_ATTN) {
                    // even col = den (row 2u of EKi), odd col = num (row 2u+1)
                    const float partner = __shfl_xor(c, 1);
                    if ((col & 1) == 0) {
                        const int u = col >> 1;
                        const float sv = b2f(((const bf16*)e1)[(size_t)row * (N/2) + u]);
                        ((bf16*)o0)[(size_t)row * (N/2) + u] = f2b(sv * (partner / c));
                    }
                } else if constexpr (EPI == EPI_GLU) {
                    // even col = x1 (row 2d of Wi), odd col = gate
                    const float partner = __shfl_xor(c, 1);
                    if ((col & 1) == 0) {
                        const float g = partner;
                        const float sp = (g > 20.f) ? g : log1pf(expf(g));
                        ((bf16*)o0)[(size_t)row * (N/2) + (col >> 1)] =
                            f2b(c * (g * tanhf(sp)));
                    }
                } else { // EPI_FC2SUM
                    const size_t idx = (size_t)row * N + col;
                    ((float*)o0)[idx] = c + e1[idx] + e2[idx];
                }
            }
        }
    }
}

// ---------------- launch ----------------
extern "C" void kernel_launch(void* const* d_in, const int* in_sizes, int n_in,
                              void* d_out, int out_size, void* d_ws, size_t ws_size,
                              hipStream_t stream) {
    const float* data  = (const float*)d_in[0];
    const float* qkv_w = (const float*)d_in[1];
    const float* qkv_b = (const float*)d_in[2];
    const float* pos_b = (const float*)d_in[3];
    const float* out_w = (const float*)d_in[4];
    const float* out_b = (const float*)d_in[5];
    const float* fc1_w = (const float*)d_in[6];
    const float* fc1_b = (const float*)d_in[7];
    const float* fc2_w = (const float*)d_in[8];
    const float* fc2_b = (const float*)d_in[9];
    float* out = (float*)d_out;

    char* ws = (char*)d_ws;
    const size_t MB = 1024ull * 1024ull;
    bf16* h    = (bf16*)(ws);              // 0..32MB    LN(data)
    bf16* Wb   = (bf16*)(ws + 32*MB);      // 32..40MB   exp(pos_bias)
    bf16* sq   = (bf16*)(ws + 40*MB);      // 40..72MB   sigmoid(q)
    char* slotA = ws + 72*MB;              // 72..136MB  ek|vv -> Y
    char* slotB = ws + 136*MB;             // 136..200MB EKi -> ffin
    bf16* qkvw_b  = (bf16*)(ws + 200*MB);
    bf16* outw_b  = qkvw_b + (size_t)3072 * 1024;
    bf16* fc1wi_b = outw_b + (size_t)1024 * 1024;   // interleaved fc1 weights
    bf16* fc2w_b  = fc1wi_b + (size_t)2048 * 1024;

    bf16* ek   = (bf16*)slotA;             // [2048, 8192]
    bf16* vv   = (bf16*)(slotA + 32*MB);
    bf16* EKi  = (bf16*)slotB;             // [16384, 2048] interleaved den/num rows
    bf16* Y    = (bf16*)slotA;             // [2048, 8192] (after transpose, ek/vv dead)
    bf16* ffin = (bf16*)slotB;             // [16384, 1024] (after attn gemm, EKi dead)

    ln_kernel<<<MROWS, 256, 0, stream>>>(data, h);
    expw_kernel<<<4096, 256, 0, stream>>>(pos_b, Wb, T_DIM * T_DIM / 4);
    cvt_kernel<<<3072, 256, 0, stream>>>(qkv_w, qkvw_b, 3072 * 1024 / 4);
    cvt_kernel<<<1024, 256, 0, stream>>>(out_w, outw_b, 1024 * 1024 / 4);
    cvt_ilv_kernel<<<2048, 256, 0, stream>>>(fc1_w, fc1wi_b);
    cvt_kernel<<<1024, 256, 0, stream>>>(fc2_w, fc2w_b, 1024 * 1024 / 4);

    // QKV projection -> sigmoid(q), exp(k), v
    gemm8<MROWS, 3072, 1024, EPI_QKV><<<dim3(12, 64), 512, 0, stream>>>(
        h, qkvw_b, qkv_b, sq, ek, vv, nullptr, nullptr);

    // ek, ek*v transposed+interleaved to [16384,2048]
    transpose_ekv<<<dim3(128, 32), 256, 0, stream>>>(
        (const unsigned short*)ek, (const unsigned short*)vv,
        (unsigned short*)EKi);

    // attn GEMM fused: Y = sigmoid(q) * num/den, Y bf16 [2048,8192]
    gemm8<T_DIM, 2 * N8, T_DIM, EPI_ATTN><<<dim3(64, 8), 512, 0, stream>>>(
        Wb, EKi, nullptr, Y, nullptr, nullptr, (const float*)sq, nullptr);

    // out projection -> aft stored in d_out (f32)
    gemm8<MROWS, 1024, 1024, EPI_BIAS_F32><<<dim3(4, 64), 512, 0, stream>>>(
        Y, outw_b, out_b, out, nullptr, nullptr, nullptr, nullptr);

    // fc1 fused GLU: ffin = x1 * mish(gate), bf16 [16384,1024]
    gemm8<MROWS, 2048, 1024, EPI_GLU><<<dim3(8, 64), 512, 0, stream>>>(
        h, fc1wi_b, fc1_b, ffin, nullptr, nullptr, nullptr, nullptr);

    // fc2 + residual: out = c + data + aft(d_out)
    gemm8<MROWS, 1024, 1024, EPI_FC2SUM><<<dim3(4, 64), 512, 0, stream>>>(
        ffin, fc2w_b, fc2_b, out, nullptr, nullptr, data, out);
}